// Round 1
// baseline (910.300 us; speedup 1.0000x reference)
//
#include <hip/hip_runtime.h>
#include <math.h>

// Batched 10-qubit statevector sim: one wave (64 lanes) per batch element.
// State = 1024 complex amps = 16 complex per lane in registers.
// Amp index a = (lane << 4) | r  (r = register slot 0..15).
// Wire w acts on bit b = 9-w of a:  b<4  -> in-register 2x2;
//                                   b>=4 -> cross-lane via __shfl_xor(1<<(b-4)).

constexpr int NQ = 10;
constexpr int NDEPTH = 6;
constexpr int NCLS = 16;

// ---- RX: n0 = c*a0 - i s*a1 ; n1 = -i s*a0 + c*a1 ----
// Cross-lane form is symmetric in the pair: re' = c*re_mine + s*im_partner,
// im' = c*im_mine - s*re_partner  (holds for both the bit=0 and bit=1 lane).
template<int MASK>
__device__ __forceinline__ void cross_rx(float (&sr)[16], float (&si)[16], float c, float s) {
#pragma unroll
    for (int r = 0; r < 16; ++r) {
        float pre = __shfl_xor(sr[r], MASK, 64);
        float pim = __shfl_xor(si[r], MASK, 64);
        sr[r] = fmaf(c, sr[r], s * pim);
        si[r] = fmaf(c, si[r], -s * pre);
    }
}

// ---- RY: n0 = c*a0 - s*a1 ; n1 = s*a0 + c*a1 (real rotation on re and im) ----
template<int MASK>
__device__ __forceinline__ void cross_ry(float (&sr)[16], float (&si)[16], float c, float s, int lane) {
    const float t = (lane & MASK) ? s : -s;   // bit=0 lane: c*mine - s*partner ; bit=1: c*mine + s*partner
#pragma unroll
    for (int r = 0; r < 16; ++r) {
        float pre = __shfl_xor(sr[r], MASK, 64);
        float pim = __shfl_xor(si[r], MASK, 64);
        sr[r] = fmaf(t, pre, c * sr[r]);
        si[r] = fmaf(t, pim, c * si[r]);
    }
}

template<int B>
__device__ __forceinline__ void local_rx(float (&sr)[16], float (&si)[16], float c, float s) {
#pragma unroll
    for (int r0 = 0; r0 < 16; ++r0) {
        if ((r0 & (1 << B)) == 0) {
            const int r1 = r0 | (1 << B);
            const float a0r = sr[r0], a0i = si[r0], a1r = sr[r1], a1i = si[r1];
            sr[r0] = fmaf(c, a0r,  s * a1i);
            si[r0] = fmaf(c, a0i, -s * a1r);
            sr[r1] = fmaf(c, a1r,  s * a0i);
            si[r1] = fmaf(c, a1i, -s * a0r);
        }
    }
}

template<int B>
__device__ __forceinline__ void local_ry(float (&sr)[16], float (&si)[16], float c, float s) {
#pragma unroll
    for (int r0 = 0; r0 < 16; ++r0) {
        if ((r0 & (1 << B)) == 0) {
            const int r1 = r0 | (1 << B);
            const float a0r = sr[r0], a0i = si[r0], a1r = sr[r1], a1i = si[r1];
            sr[r0] = fmaf(c, a0r, -s * a1r);
            si[r0] = fmaf(c, a0i, -s * a1i);
            sr[r1] = fmaf(s, a0r,  c * a1r);
            si[r1] = fmaf(s, a0i,  c * a1i);
        }
    }
}

template<int W>
__device__ __forceinline__ void apply_rx(float (&sr)[16], float (&si)[16], float c, float s) {
    constexpr int B = 9 - W;
    if constexpr (B >= 4) cross_rx<(1 << (B - 4))>(sr, si, c, s);
    else                  local_rx<B>(sr, si, c, s);
}

template<int W>
__device__ __forceinline__ void apply_ry(float (&sr)[16], float (&si)[16], float c, float s, int lane) {
    constexpr int B = 9 - W;
    if constexpr (B >= 4) cross_ry<(1 << (B - 4))>(sr, si, c, s, lane);
    else                  local_ry<B>(sr, si, c, s);
}

__global__ void __launch_bounds__(256) qnn_kernel(
    const float* __restrict__ x,       // (B, 10)
    const float* __restrict__ params,  // (6, 10)
    const float* __restrict__ w_cls,   // (16, 10)
    const float* __restrict__ b_cls,   // (16,)
    float* __restrict__ out,           // (B, 16)
    int batch)
{
    const int lane = threadIdx.x & 63;
    const int wid  = threadIdx.x >> 6;
    const int b    = blockIdx.x * (blockDim.x >> 6) + wid;
    if (b >= batch) return;

    float sr[16], si[16];
#pragma unroll
    for (int r = 0; r < 16; ++r) { sr[r] = 0.f; si[r] = 0.f; }
    if (lane == 0) sr[0] = 1.f;   // |0...0>

    // ---- RX encoding layer: lane l (<10) owns angle l; broadcast by shuffle ----
    float cx, sx;
    {
        const int l = (lane < NQ) ? lane : 0;
        sincosf(x[b * NQ + l] * 0.5f, &sx, &cx);
    }
#define RX_W(W) apply_rx<W>(sr, si, __shfl(cx, (W), 64), __shfl(sx, (W), 64))
    RX_W(0); RX_W(1); RX_W(2); RX_W(3); RX_W(4);
    RX_W(5); RX_W(6); RX_W(7); RX_W(8); RX_W(9);
#undef RX_W

    // ---- RY params: lane l (<60) owns params[l]; broadcast by shuffle ----
    float cp, sp;
    {
        const int l = (lane < NDEPTH * NQ) ? lane : 0;
        sincosf(params[l] * 0.5f, &sp, &cp);
    }

    // ---- fused CZ-chain sign: parity of adjacent '11' pairs in a = (lane<<4)|r ----
    // pairs within lane bits (uniform per lane) -> ls; boundary pair (r bit3, lane bit0) -> lsb;
    // pairs within r handled as compile-time constants below.
    const int lpar = __popc(lane & (lane >> 1) & 0x1F) & 1;
    const float ls  = lpar ? -1.f : 1.f;
    const float lsb = (lane & 1) ? -ls : ls;

#pragma unroll
    for (int d = 0; d < NDEPTH; ++d) {
        const int base = d * NQ;
#define RY_W(W) apply_ry<W>(sr, si, __shfl(cp, base + (W), 64), __shfl(sp, base + (W), 64), lane)
        RY_W(0); RY_W(1); RY_W(2); RY_W(3); RY_W(4);
        RY_W(5); RY_W(6); RY_W(7); RY_W(8); RY_W(9);
#undef RY_W
        // all 9 CZs of this layer as one sign pass
#pragma unroll
        for (int r = 0; r < 16; ++r) {
            const int cr = __popc(r & (r >> 1) & 7) & 1;   // compile-time per r
            float f = (r & 8) ? lsb : ls;
            if (cr) f = -f;
            sr[r] *= f; si[r] *= f;
        }
    }

    // ---- probabilities & Z expectations ----
    float p[16];
#pragma unroll
    for (int r = 0; r < 16; ++r) p[r] = fmaf(sr[r], sr[r], si[r] * si[r]);

    float pt = 0.f;
#pragma unroll
    for (int r = 0; r < 16; ++r) pt += p[r];

    float e[NQ];
#pragma unroll
    for (int q = 0; q < 6; ++q) {               // wires 0..5 -> lane bit (5-q)
        e[q] = ((lane >> (5 - q)) & 1) ? -pt : pt;
    }
#pragma unroll
    for (int q = 6; q < 10; ++q) {              // wires 6..9 -> r bit (9-q)
        const int bb = 9 - q;
        float acc = 0.f;
#pragma unroll
        for (int r = 0; r < 16; ++r) acc += ((r >> bb) & 1) ? -p[r] : p[r];
        e[q] = acc;
    }

    // butterfly reduce each expectation across the wave
#pragma unroll
    for (int q = 0; q < NQ; ++q) {
#pragma unroll
        for (int m = 1; m < 64; m <<= 1) e[q] += __shfl_xor(e[q], m, 64);
    }

    // ---- linear head: lane k (<16) emits class k ----
    if (lane < NCLS) {
        float acc = b_cls[lane];
#pragma unroll
        for (int q = 0; q < NQ; ++q) acc = fmaf(e[q], w_cls[lane * NQ + q], acc);
        out[b * NCLS + lane] = acc;
    }
}

extern "C" void kernel_launch(void* const* d_in, const int* in_sizes, int n_in,
                              void* d_out, int out_size, void* d_ws, size_t ws_size,
                              hipStream_t stream) {
    const float* x      = (const float*)d_in[0];
    const float* params = (const float*)d_in[1];
    const float* w_cls  = (const float*)d_in[2];
    const float* b_cls  = (const float*)d_in[3];
    float* out = (float*)d_out;

    const int batch = in_sizes[0] / NQ;          // 65536
    const int WAVES_PER_BLOCK = 4;               // 256 threads
    dim3 block(64 * WAVES_PER_BLOCK);
    dim3 grid((batch + WAVES_PER_BLOCK - 1) / WAVES_PER_BLOCK);
    hipLaunchKernelGGL(qnn_kernel, grid, block, 0, stream, x, params, w_cls, b_cls, out, batch);
}

// Round 3
// 592.497 us; speedup vs baseline: 1.5364x; 1.5364x over previous
//
#include <hip/hip_runtime.h>
#include <math.h>

// Batched 10-qubit statevector sim: one wave per batch element.
// State = 1024 complex amps = 16 float2 (re,im) per lane in registers.
// Amp index a = (lane << 4) | r. Wire w acts on bit 9-w of a:
//   bit<4  -> in-register 2x2 (packed f32 math),
//   bit>=4 -> cross-lane, lane mask 1<<(bit-4):
//     mask 1,2 : DPP quad_perm   (VALU)
//     mask 8   : DPP row_ror:8   (VALU; ror by 8 in a 16-row == xor 8)
//     mask 4   : ds_swizzle      (kept on the otherwise-idle LDS pipe)
//     mask 16  : v_permlane16_swap + cndmask (VALU, gfx950)
//     mask 32  : v_permlane32_swap + cndmask (VALU, gfx950)
// Round-1 counters showed the DS pipe saturated (1.5k ds-ops/wave ~= 920us)
// with VALU only 52% busy — round 2+ moves shuffles to the VALU pipe.
// Round-2 compile fix: permlane*_swap builtins return ext_vector<uint,2>;
// index with [0]/[1], not .x/.y.

typedef float v2f __attribute__((ext_vector_type(2)));

constexpr int NQ = 10;
constexpr int NDEPTH = 6;
constexpr int NCLS = 16;

__device__ __forceinline__ float i2f(int i) { return __builtin_bit_cast(float, i); }
__device__ __forceinline__ int   f2i(float f) { return __builtin_bit_cast(int, f); }

// value of v at lane (lane ^ MASK)
template<int MASK>
__device__ __forceinline__ float xp(float v, int lane) {
    if constexpr (MASK == 1) {                     // quad_perm [1,0,3,2]
        int i = f2i(v);
        return i2f(__builtin_amdgcn_update_dpp(i, i, 0xB1, 0xF, 0xF, false));
    } else if constexpr (MASK == 2) {              // quad_perm [2,3,0,1]
        int i = f2i(v);
        return i2f(__builtin_amdgcn_update_dpp(i, i, 0x4E, 0xF, 0xF, false));
    } else if constexpr (MASK == 8) {              // row_ror:8 == xor 8 in 16-row
        int i = f2i(v);
        return i2f(__builtin_amdgcn_update_dpp(i, i, 0x128, 0xF, 0xF, false));
    } else if constexpr (MASK == 4) {              // keep on (idle) DS pipe
        return __shfl_xor(v, 4, 64);
    } else if constexpr (MASK == 16) {
#if __has_builtin(__builtin_amdgcn_permlane16_swap)
        unsigned u = (unsigned)f2i(v);
        auto pr = __builtin_amdgcn_permlane16_swap(u, u, false, false);
        // same-input swap: pr[0] rows = {g0,g0,g2,g2}, pr[1] rows = {g1,g1,g3,g3}
        return i2f((int)((lane & 16) ? pr[0] : pr[1]));
#else
        return __shfl_xor(v, 16, 64);
#endif
    } else {  // MASK == 32
#if __has_builtin(__builtin_amdgcn_permlane32_swap)
        unsigned u = (unsigned)f2i(v);
        auto pr = __builtin_amdgcn_permlane32_swap(u, u, false, false);
        // same-input swap: pr[0] halves = {lo,lo}, pr[1] halves = {hi,hi}
        return i2f((int)((lane & 32) ? pr[0] : pr[1]));
#else
        return __shfl_xor(v, 32, 64);
#endif
    }
}

// ---- RY cross-lane: new = c*mine + t*partner, t = +s if lane-bit set else -s ----
template<int MASK>
__device__ __forceinline__ void cross_ry(v2f (&st)[16], float c, float sv, int lane) {
    const float t = (lane & MASK) ? sv : -sv;
#pragma unroll
    for (int r = 0; r < 16; ++r) {
        v2f p;
        p.x = xp<MASK>(st[r].x, lane);
        p.y = xp<MASK>(st[r].y, lane);
        st[r] = c * st[r] + t * p;                 // v_pk_mul + v_pk_fma
    }
}

// ---- RX cross-lane: re' = c*re + s*pim ; im' = c*im - s*pre (both halves) ----
template<int MASK>
__device__ __forceinline__ void cross_rx(v2f (&st)[16], float c, float sv, int lane) {
    const v2f co = { sv, -sv };
#pragma unroll
    for (int r = 0; r < 16; ++r) {
        v2f psw;
        psw.x = xp<MASK>(st[r].y, lane);           // partner im
        psw.y = xp<MASK>(st[r].x, lane);           // partner re
        st[r] = c * st[r] + co * psw;
    }
}

template<int B>
__device__ __forceinline__ void local_ry(v2f (&st)[16], float c, float sv) {
#pragma unroll
    for (int r0 = 0; r0 < 16; ++r0) {
        if ((r0 & (1 << B)) == 0) {
            const int r1 = r0 | (1 << B);
            const v2f a0 = st[r0], a1 = st[r1];
            st[r0] = c * a0 - sv * a1;
            st[r1] = sv * a0 + c * a1;
        }
    }
}

template<int B>
__device__ __forceinline__ void local_rx(v2f (&st)[16], float c, float sv) {
    const v2f co = { sv, -sv };
#pragma unroll
    for (int r0 = 0; r0 < 16; ++r0) {
        if ((r0 & (1 << B)) == 0) {
            const int r1 = r0 | (1 << B);
            const v2f a0 = st[r0], a1 = st[r1];
            const v2f a0s = a0.yx, a1s = a1.yx;
            st[r0] = c * a0 + co * a1s;            // (c*a0r + s*a1i, c*a0i - s*a1r)
            st[r1] = c * a1 + co * a0s;
        }
    }
}

template<int W>
__device__ __forceinline__ void apply_rx(v2f (&st)[16], float c, float s, int lane) {
    constexpr int B = 9 - W;
    if constexpr (B >= 4) cross_rx<(1 << (B - 4))>(st, c, s, lane);
    else                  local_rx<B>(st, c, s);
}

template<int W>
__device__ __forceinline__ void apply_ry(v2f (&st)[16], float c, float s, int lane) {
    constexpr int B = 9 - W;
    if constexpr (B >= 4) cross_ry<(1 << (B - 4))>(st, c, s, lane);
    else                  local_ry<B>(st, c, s);
}

__device__ __forceinline__ float rdlane(float v, int l) {
    return i2f(__builtin_amdgcn_readlane(f2i(v), l));   // SALU broadcast, no ds op
}

__device__ __forceinline__ float wave_sum(float v, int lane) {
    v += xp<1>(v, lane);
    v += xp<2>(v, lane);
    v += xp<4>(v, lane);
    v += xp<8>(v, lane);
    v += xp<16>(v, lane);
    v += xp<32>(v, lane);
    return v;
}

__global__ void __launch_bounds__(256) qnn_kernel(
    const float* __restrict__ x,       // (B, 10)
    const float* __restrict__ params,  // (6, 10)
    const float* __restrict__ w_cls,   // (16, 10)
    const float* __restrict__ b_cls,   // (16,)
    float* __restrict__ out,           // (B, 16)
    int batch)
{
    const int lane = threadIdx.x & 63;
    const int wid  = threadIdx.x >> 6;
    const int b    = blockIdx.x * (blockDim.x >> 6) + wid;
    if (b >= batch) return;

    v2f st[16];
#pragma unroll
    for (int r = 0; r < 16; ++r) st[r] = (v2f){0.f, 0.f};
    if (lane == 0) st[0].x = 1.f;      // |0...0>

    // ---- RX encoding: lane l (<10) owns angle l; broadcast via v_readlane ----
    float cx, sx;
    {
        const int l = (lane < NQ) ? lane : 0;
        sincosf(x[b * NQ + l] * 0.5f, &sx, &cx);
    }
#define RX_W(W) apply_rx<W>(st, rdlane(cx, (W)), rdlane(sx, (W)), lane)
    RX_W(0); RX_W(1); RX_W(2); RX_W(3); RX_W(4);
    RX_W(5); RX_W(6); RX_W(7); RX_W(8); RX_W(9);
#undef RX_W

    // ---- RY params: lane l (<60) owns params[l] ----
    float cp, sp;
    {
        const int l = (lane < NDEPTH * NQ) ? lane : 0;
        sincosf(params[l] * 0.5f, &sp, &cp);
    }

    // ---- fused CZ-chain sign (validated round 1) ----
    const int lpar = __popc(lane & (lane >> 1) & 0x1F) & 1;
    const float ls  = lpar ? -1.f : 1.f;
    const float lsb = (lane & 1) ? -ls : ls;

#pragma unroll
    for (int d = 0; d < NDEPTH; ++d) {
        const int base = d * NQ;
#define RY_W(W) apply_ry<W>(st, rdlane(cp, base + (W)), rdlane(sp, base + (W)), lane)
        RY_W(0); RY_W(1); RY_W(2); RY_W(3); RY_W(4);
        RY_W(5); RY_W(6); RY_W(7); RY_W(8); RY_W(9);
#undef RY_W
#pragma unroll
        for (int r = 0; r < 16; ++r) {
            const int cr = __popc(r & (r >> 1) & 7) & 1;
            float f = (r & 8) ? lsb : ls;
            if (cr) f = -f;
            st[r] = st[r] * f;                      // v_pk_mul
        }
    }

    // ---- probabilities & Z expectations ----
    float pt = 0.f, e6 = 0.f, e7 = 0.f, e8 = 0.f, e9 = 0.f;
#pragma unroll
    for (int r = 0; r < 16; ++r) {
        const float pp = st[r].x * st[r].x + st[r].y * st[r].y;
        pt += pp;
        e9 += (r & 1) ? -pp : pp;
        e8 += (r & 2) ? -pp : pp;
        e7 += (r & 4) ? -pp : pp;
        e6 += (r & 8) ? -pp : pp;
    }

    float e[NQ];
#pragma unroll
    for (int q = 0; q < 6; ++q)                    // wires 0..5 -> lane bit (5-q)
        e[q] = ((lane >> (5 - q)) & 1) ? -pt : pt;
    e[6] = e6; e[7] = e7; e[8] = e8; e[9] = e9;

#pragma unroll
    for (int q = 0; q < NQ; ++q) e[q] = wave_sum(e[q], lane);

    // ---- linear head: lane k (<16) emits class k ----
    if (lane < NCLS) {
        float acc = b_cls[lane];
#pragma unroll
        for (int q = 0; q < NQ; ++q) acc = fmaf(e[q], w_cls[lane * NQ + q], acc);
        out[b * NCLS + lane] = acc;
    }
}

extern "C" void kernel_launch(void* const* d_in, const int* in_sizes, int n_in,
                              void* d_out, int out_size, void* d_ws, size_t ws_size,
                              hipStream_t stream) {
    const float* x      = (const float*)d_in[0];
    const float* params = (const float*)d_in[1];
    const float* w_cls  = (const float*)d_in[2];
    const float* b_cls  = (const float*)d_in[3];
    float* out = (float*)d_out;

    const int batch = in_sizes[0] / NQ;            // 65536
    const int WAVES_PER_BLOCK = 4;                 // 256 threads
    dim3 block(64 * WAVES_PER_BLOCK);
    dim3 grid((batch + WAVES_PER_BLOCK - 1) / WAVES_PER_BLOCK);
    hipLaunchKernelGGL(qnn_kernel, grid, block, 0, stream, x, params, w_cls, b_cls, out, batch);
}

// Round 4
// 515.796 us; speedup vs baseline: 1.7648x; 1.1487x over previous
//
#include <hip/hip_runtime.h>
#include <math.h>

// Batched 10-qubit statevector sim: one wave per batch element.
// State = 1024 complex amps = 16 float2 (re,im) per lane in registers.
// Amp index a = (lane << 4) | r. Wire w acts on bit 9-w of a:
//   bit<4  -> in-register 2x2 (packed f32 math),
//   bit>=4 -> cross-lane, lane mask 1<<(bit-4):
//     mask 32  : v_permlane32_swap PAIR trick (no cndmask, no movs)
//     mask 16  : v_permlane16_swap PAIR trick
//     mask 8   : DPP row_ror:8
//     mask 4   : ds_swizzle (kept on the otherwise-idle LDS pipe)
//     mask 1,2 : DPP quad_perm
// Round-3 counters: VALUBusy ~104% (saturated), HBM 0.08% -> pure VALU-bound.
// Round 4 cuts VALU ops: permlane swaps used as designed on REGISTER PAIRS:
//   swap(a,b): A={a.lo,b.lo} B={a.hi,b.hi} (row-aligned bit0/bit1 data) ->
//   C=c*A-s*B, D=s*A+c*B -> swap(C,D) restores layout: C'=a', D'=b'.
// 2 VALU ops/float vs ~5-6 for broadcast+select. Packed v2f math throughout.

typedef float v2f __attribute__((ext_vector_type(2)));
typedef unsigned int u32;

constexpr int NQ = 10;
constexpr int NDEPTH = 6;
constexpr int NCLS = 16;

__device__ __forceinline__ float i2f(int i) { return __builtin_bit_cast(float, i); }
__device__ __forceinline__ int   f2i(float f) { return __builtin_bit_cast(int, f); }
__device__ __forceinline__ u32   f2u(float f) { return __builtin_bit_cast(u32, f); }
__device__ __forceinline__ float u2f(u32 u)   { return __builtin_bit_cast(float, u); }

// ---- two-register half-exchange (gfx950) ----
// M=32: new_a = {a.lo32, b.lo32}, new_b = {a.hi32, b.hi32}
// M=16: new_a = {a.r0, b.r0, a.r2, b.r2}, new_b = {a.r1, b.r1, a.r3, b.r3} (r = 16-lane rows)
template<int M>
__device__ __forceinline__ void plswap(float& a, float& b) {
    if constexpr (M == 32) {
        auto pr = __builtin_amdgcn_permlane32_swap(f2u(a), f2u(b), false, false);
        a = u2f(pr[0]); b = u2f(pr[1]);
    } else {
        auto pr = __builtin_amdgcn_permlane16_swap(f2u(a), f2u(b), false, false);
        a = u2f(pr[0]); b = u2f(pr[1]);
    }
}

// ---- RY cross gate on a PAIR of state regs via swap trick (M = 16 or 32) ----
template<int M>
__device__ __forceinline__ void cross_ry_pair(v2f& va, v2f& vb, float c, float sv) {
    float Ax = va.x, Bx = vb.x, Ay = va.y, By = vb.y;
    plswap<M>(Ax, Bx);                 // A* = bit0 rows, B* = bit1 rows (row-aligned)
    plswap<M>(Ay, By);
    const v2f A = {Ax, Ay}, B = {Bx, By};
    v2f C = c * A - sv * B;            // n(bit0) values, rows of a and b interleaved
    v2f D = sv * A + c * B;            // n(bit1) values
    float Cx = C.x, Dx = D.x, Cy = C.y, Dy = D.y;
    plswap<M>(Cx, Dx);                 // un-interleave: C' = new a, D' = new b
    plswap<M>(Cy, Dy);
    va = (v2f){Cx, Cy}; vb = (v2f){Dx, Dy};
}

// ---- RX cross gate pair version: re' = c*re + s*im_p ; im' = c*im - s*re_p ----
template<int M>
__device__ __forceinline__ void cross_rx_pair(v2f& va, v2f& vb, float c, float sv) {
    float Ax = va.x, Bx = vb.x, Ay = va.y, By = vb.y;
    plswap<M>(Ax, Bx);
    plswap<M>(Ay, By);
    const v2f co = { sv, -sv };
    const v2f A = {Ax, Ay}, B = {Bx, By};
    v2f C = c * A + co * (v2f){By, Bx};    // (c*Ar + s*Bi, c*Ai - s*Br)
    v2f D = c * B + co * (v2f){Ay, Ax};    // (c*Br + s*Ai, c*Bi - s*Ar)
    float Cx = C.x, Dx = D.x, Cy = C.y, Dy = D.y;
    plswap<M>(Cx, Dx);
    plswap<M>(Cy, Dy);
    va = (v2f){Cx, Cy}; vb = (v2f){Dx, Dy};
}

// ---- partner fetch for masks 1,2,4,8 (DPP / ds_swizzle) ----
template<int MASK>
__device__ __forceinline__ float xp(float v, int lane) {
    if constexpr (MASK == 1) {                     // quad_perm [1,0,3,2]
        int i = f2i(v);
        return i2f(__builtin_amdgcn_update_dpp(i, i, 0xB1, 0xF, 0xF, false));
    } else if constexpr (MASK == 2) {              // quad_perm [2,3,0,1]
        int i = f2i(v);
        return i2f(__builtin_amdgcn_update_dpp(i, i, 0x4E, 0xF, 0xF, false));
    } else if constexpr (MASK == 8) {              // row_ror:8 == xor 8 in 16-row
        int i = f2i(v);
        return i2f(__builtin_amdgcn_update_dpp(i, i, 0x128, 0xF, 0xF, false));
    } else if constexpr (MASK == 4) {              // keep on (idle) DS pipe
        return __shfl_xor(v, 4, 64);
    } else if constexpr (MASK == 16) {
        u32 u = f2u(v);
        auto pr = __builtin_amdgcn_permlane16_swap(u, u, false, false);
        return u2f((lane & 16) ? pr[0] : pr[1]);
    } else {  // MASK == 32
        u32 u = f2u(v);
        auto pr = __builtin_amdgcn_permlane32_swap(u, u, false, false);
        return u2f((lane & 32) ? pr[0] : pr[1]);
    }
}

template<int MASK>
__device__ __forceinline__ void cross_ry(v2f (&st)[16], float c, float sv, int lane) {
    const float t = (lane & MASK) ? sv : -sv;
#pragma unroll
    for (int r = 0; r < 16; ++r) {
        v2f p;
        p.x = xp<MASK>(st[r].x, lane);
        p.y = xp<MASK>(st[r].y, lane);
        st[r] = c * st[r] + t * p;                 // v_pk_mul + v_pk_fma
    }
}

template<int MASK>
__device__ __forceinline__ void cross_rx(v2f (&st)[16], float c, float sv, int lane) {
    const v2f co = { sv, -sv };
#pragma unroll
    for (int r = 0; r < 16; ++r) {
        v2f psw;
        psw.x = xp<MASK>(st[r].y, lane);           // partner im
        psw.y = xp<MASK>(st[r].x, lane);           // partner re
        st[r] = c * st[r] + co * psw;
    }
}

template<int B>
__device__ __forceinline__ void local_ry(v2f (&st)[16], float c, float sv) {
#pragma unroll
    for (int r0 = 0; r0 < 16; ++r0) {
        if ((r0 & (1 << B)) == 0) {
            const int r1 = r0 | (1 << B);
            const v2f a0 = st[r0], a1 = st[r1];
            st[r0] = c * a0 - sv * a1;
            st[r1] = sv * a0 + c * a1;
        }
    }
}

template<int B>
__device__ __forceinline__ void local_rx(v2f (&st)[16], float c, float sv) {
    const v2f co = { sv, -sv };
#pragma unroll
    for (int r0 = 0; r0 < 16; ++r0) {
        if ((r0 & (1 << B)) == 0) {
            const int r1 = r0 | (1 << B);
            const v2f a0 = st[r0], a1 = st[r1];
            const v2f a0s = a0.yx, a1s = a1.yx;
            st[r0] = c * a0 + co * a1s;            // (c*a0r + s*a1i, c*a0i - s*a1r)
            st[r1] = c * a1 + co * a0s;
        }
    }
}

template<int W>
__device__ __forceinline__ void apply_rx(v2f (&st)[16], float c, float s, int lane) {
    constexpr int B = 9 - W;
    if constexpr (B == 9) {
#pragma unroll
        for (int r = 0; r < 16; r += 2) cross_rx_pair<32>(st[r], st[r+1], c, s);
    } else if constexpr (B == 8) {
#pragma unroll
        for (int r = 0; r < 16; r += 2) cross_rx_pair<16>(st[r], st[r+1], c, s);
    } else if constexpr (B >= 4) {
        cross_rx<(1 << (B - 4))>(st, c, s, lane);
    } else {
        local_rx<B>(st, c, s);
    }
}

template<int W>
__device__ __forceinline__ void apply_ry(v2f (&st)[16], float c, float s, int lane) {
    constexpr int B = 9 - W;
    if constexpr (B == 9) {
#pragma unroll
        for (int r = 0; r < 16; r += 2) cross_ry_pair<32>(st[r], st[r+1], c, s);
    } else if constexpr (B == 8) {
#pragma unroll
        for (int r = 0; r < 16; r += 2) cross_ry_pair<16>(st[r], st[r+1], c, s);
    } else if constexpr (B >= 4) {
        cross_ry<(1 << (B - 4))>(st, c, s, lane);
    } else {
        local_ry<B>(st, c, s);
    }
}

__device__ __forceinline__ float rdlane(float v, int l) {
    return i2f(__builtin_amdgcn_readlane(f2i(v), l));   // SALU broadcast
}

__device__ __forceinline__ float wave_sum(float v, int lane) {
    v += xp<1>(v, lane);
    v += xp<2>(v, lane);
    v += xp<4>(v, lane);
    v += xp<8>(v, lane);
    v += xp<16>(v, lane);
    v += xp<32>(v, lane);
    return v;
}

__global__ void __launch_bounds__(256) qnn_kernel(
    const float* __restrict__ x,       // (B, 10)
    const float* __restrict__ params,  // (6, 10)
    const float* __restrict__ w_cls,   // (16, 10)
    const float* __restrict__ b_cls,   // (16,)
    float* __restrict__ out,           // (B, 16)
    int batch)
{
    const int lane = threadIdx.x & 63;
    const int wid  = threadIdx.x >> 6;
    const int b    = blockIdx.x * (blockDim.x >> 6) + wid;
    if (b >= batch) return;

    v2f st[16];
#pragma unroll
    for (int r = 0; r < 16; ++r) st[r] = (v2f){0.f, 0.f};
    if (lane == 0) st[0].x = 1.f;      // |0...0>

    // ---- RX encoding: lane l (<10) owns angle l; broadcast via v_readlane ----
    float cx, sx;
    {
        const int l = (lane < NQ) ? lane : 0;
        __sincosf(x[b * NQ + l] * 0.5f, &sx, &cx);
    }
#define RX_W(W) apply_rx<W>(st, rdlane(cx, (W)), rdlane(sx, (W)), lane)
    RX_W(0); RX_W(1); RX_W(2); RX_W(3); RX_W(4);
    RX_W(5); RX_W(6); RX_W(7); RX_W(8); RX_W(9);
#undef RX_W

    // ---- RY params: lane l (<60) owns params[l] ----
    float cp, sp;
    {
        const int l = (lane < NDEPTH * NQ) ? lane : 0;
        __sincosf(params[l] * 0.5f, &sp, &cp);
    }

    // ---- fused CZ-chain sign (validated round 1) ----
    const int lpar = __popc(lane & (lane >> 1) & 0x1F) & 1;
    const float ls  = lpar ? -1.f : 1.f;
    const float lsb = (lane & 1) ? -ls : ls;

#pragma unroll
    for (int d = 0; d < NDEPTH; ++d) {
        const int base = d * NQ;
#define RY_W(W) apply_ry<W>(st, rdlane(cp, base + (W)), rdlane(sp, base + (W)), lane)
        RY_W(0); RY_W(1); RY_W(2); RY_W(3); RY_W(4);
        RY_W(5); RY_W(6); RY_W(7); RY_W(8); RY_W(9);
#undef RY_W
#pragma unroll
        for (int r = 0; r < 16; ++r) {
            const int cr = __popc(r & (r >> 1) & 7) & 1;
            float f = (r & 8) ? lsb : ls;
            if (cr) f = -f;
            st[r] = st[r] * f;                      // v_pk_mul
        }
    }

    // ---- probabilities & Z expectations ----
    float pt = 0.f, e6 = 0.f, e7 = 0.f, e8 = 0.f, e9 = 0.f;
#pragma unroll
    for (int r = 0; r < 16; ++r) {
        const float pp = st[r].x * st[r].x + st[r].y * st[r].y;
        pt += pp;
        e9 += (r & 1) ? -pp : pp;
        e8 += (r & 2) ? -pp : pp;
        e7 += (r & 4) ? -pp : pp;
        e6 += (r & 8) ? -pp : pp;
    }

    float e[NQ];
#pragma unroll
    for (int q = 0; q < 6; ++q)                    // wires 0..5 -> lane bit (5-q)
        e[q] = ((lane >> (5 - q)) & 1) ? -pt : pt;
    e[6] = e6; e[7] = e7; e[8] = e8; e[9] = e9;

#pragma unroll
    for (int q = 0; q < NQ; ++q) e[q] = wave_sum(e[q], lane);

    // ---- linear head: lane k (<16) emits class k ----
    if (lane < NCLS) {
        float acc = b_cls[lane];
#pragma unroll
        for (int q = 0; q < NQ; ++q) acc = fmaf(e[q], w_cls[lane * NQ + q], acc);
        out[b * NCLS + lane] = acc;
    }
}

extern "C" void kernel_launch(void* const* d_in, const int* in_sizes, int n_in,
                              void* d_out, int out_size, void* d_ws, size_t ws_size,
                              hipStream_t stream) {
    const float* x      = (const float*)d_in[0];
    const float* params = (const float*)d_in[1];
    const float* w_cls  = (const float*)d_in[2];
    const float* b_cls  = (const float*)d_in[3];
    float* out = (float*)d_out;

    const int batch = in_sizes[0] / NQ;            // 65536
    const int WAVES_PER_BLOCK = 4;                 // 256 threads
    dim3 block(64 * WAVES_PER_BLOCK);
    dim3 grid((batch + WAVES_PER_BLOCK - 1) / WAVES_PER_BLOCK);
    hipLaunchKernelGGL(qnn_kernel, grid, block, 0, stream, x, params, w_cls, b_cls, out, batch);
}